// Round 10
// baseline (118.434 us; speedup 1.0000x reference)
//
#include <hip/hip_runtime.h>

#define HH 1024
#define WW 1024
#define BM 32            // output rows per block
#define BN 256           // output cols per block
#define WAVES 2
#define RPT 16           // output rows per thread (BM / WAVES)
#define NR (RPT + 10)    // 26 tile rows read per wave
#define TROWS (BM + 10)  // 42 staged input rows
#define TCOLS 272        // staged floats per row (8 + 256 + 8)
#define TFLOATS (TROWS * TCOLS)        // 11424
#define NSTG ((TFLOATS + 255) / 256)   // 45 staging instructions (1 KB each)
#define LDSF (NSTG * 256)              // 11520 floats of LDS (padded)
#define NXCD 8
#define GX (WW / BN)     // 4
#define GY (HH / BM)     // 32

typedef __attribute__((address_space(1))) const float gfloat;
typedef __attribute__((address_space(3))) float sfloat;
typedef float vfloat4 __attribute__((ext_vector_type(4)));   // native vec for nontemporal

__global__ __launch_bounds__(128) void diamond_kernel(const float* __restrict__ in,
                                                      float* __restrict__ out,
                                                      int nblocks) {
    __shared__ __attribute__((aligned(16))) float tile[LDSF];

    // XCD-aware swizzle, R8 ordering (gx innermost) — proven best.
    const int wgid = blockIdx.x;
    const int k0   = (wgid % NXCD) * (nblocks / NXCD) + wgid / NXCD;
    const int b    = k0 / (GX * GY);
    const int rem  = k0 % (GX * GY);
    const int gy   = rem / GX;
    const int gx   = rem % GX;

    const int tj  = threadIdx.x;                 // lane 0..63
    const int ty  = threadIdx.y;                 // wave 0..1
    const int J0  = gx * BN;
    const int i0b = gy * BM;
    const float* __restrict__ src = in  + (size_t)b * HH * WW;
    float*       __restrict__ dst = out + (size_t)b * HH * WW;

    // ---- stage (i0b-5 .. i0b+BM+4) x (J0-8 .. J0+263) into LDS (DMA, no VGPRs)
#pragma unroll
    for (int n = 0; n < 23; ++n) {
        const int I = ty + 2 * n;                // wave-uniform predicate
        if (I < NSTG) {
            const int f = I * 256 + 4 * tj;      // flat float index in tile
            const int r = f / TCOLS;
            const int c = f - r * TCOLS;
            const int gr = (i0b + r - 5) & (HH - 1);
            const int gc = (J0 - 8 + c) & (WW - 1);   // c%4==0 -> 16B aligned
            __builtin_amdgcn_global_load_lds((gfloat*)(src + (size_t)gr * WW + gc),
                                             (sfloat*)&tile[I * 256], 16, 0, 0);
        }
    }
    __syncthreads();   // drains vmcnt(0): all DMAs landed, visible to both waves

    const float EV[6] = {1.0f,
                         0.36787944117144233f,   // e^-1
                         0.1353352832366127f,    // e^-2
                         0.049787068367863944f,  // e^-3
                         0.018315638888734179f,  // e^-4
                         0.006737946999085467f}; // e^-5

    float acc[RPT][4];
#pragma unroll
    for (int m = 0; m < RPT; ++m)
#pragma unroll
        for (int p = 0; p < 4; ++p) acc[m][p] = 0.0f;

    const int base_r = ty * RPT;   // wave's first tile row (= its first out row)

#pragma unroll
    for (int rr = 0; rr < NR; ++rr) {
        const float* trow = &tile[(base_r + rr) * TCOLS + 4 * tj];

        // 20-float window: tile cols 4tj .. 4tj+19  (s[8+p] = output col p)
        float s[20];
#pragma unroll
        for (int t = 0; t < 5; ++t) {
            float4 v = *reinterpret_cast<const float4*>(trow + 4 * t);
            s[4 * t + 0] = v.x; s[4 * t + 1] = v.y;
            s[4 * t + 2] = v.z; s[4 * t + 3] = v.w;
        }

        // level-k horizontal sums consumed on the fly:
        // level k feeds output rows m = rr-k and m = rr-10+k with weight EV[5-k]
        float Hc[4];
#pragma unroll
        for (int p = 0; p < 4; ++p) Hc[p] = s[8 + p];
        {   // k = 0, a = 5
            const int m1 = rr - 10, m2 = rr;
            if (m1 >= 0 && m1 < RPT)
#pragma unroll
                for (int p = 0; p < 4; ++p) acc[m1][p] = fmaf(EV[5], Hc[p], acc[m1][p]);
            if (m2 >= 0 && m2 < RPT)
#pragma unroll
                for (int p = 0; p < 4; ++p) acc[m2][p] = fmaf(EV[5], Hc[p], acc[m2][p]);
        }
#pragma unroll
        for (int k = 1; k <= 4; ++k) {
#pragma unroll
            for (int p = 0; p < 4; ++p)
                Hc[p] = fmaf(EV[k], s[8 + p - k] + s[8 + p + k], Hc[p]);
            const int a = 5 - k;
            const int m1 = rr - 10 + k, m2 = rr - k;
            if (m1 >= 0 && m1 < RPT)
#pragma unroll
                for (int p = 0; p < 4; ++p) acc[m1][p] = fmaf(EV[a], Hc[p], acc[m1][p]);
            if (m2 >= 0 && m2 < RPT && m2 != m1)
#pragma unroll
                for (int p = 0; p < 4; ++p) acc[m2][p] = fmaf(EV[a], Hc[p], acc[m2][p]);
        }
        {   // k = 5 -> center row (a = 0): weight 1, subtract the self term
#pragma unroll
            for (int p = 0; p < 4; ++p)
                Hc[p] = fmaf(EV[5], s[8 + p - 5] + s[8 + p + 5], Hc[p]);
            const int m = rr - 5;
            if (m >= 0 && m < RPT)
#pragma unroll
                for (int p = 0; p < 4; ++p) acc[m][p] += Hc[p] - s[8 + p];
        }
    }

    // non-temporal stores: output is never re-read
#pragma unroll
    for (int m = 0; m < RPT; ++m) {
        vfloat4 v = {acc[m][0], acc[m][1], acc[m][2], acc[m][3]};
        __builtin_nontemporal_store(
            v, reinterpret_cast<vfloat4*>(dst + (size_t)(i0b + base_r + m) * WW + J0 + 4 * tj));
    }
}

extern "C" void kernel_launch(void* const* d_in, const int* in_sizes, int n_in,
                              void* d_out, int out_size, void* d_ws, size_t ws_size,
                              hipStream_t stream) {
    const float* in  = (const float*)d_in[0];
    float*       out = (float*)d_out;
    const int B = in_sizes[0] / (HH * WW);   // 64
    const int nblocks = GX * GY * B;         // 8192, divisible by 8
    dim3 block(64, WAVES, 1);
    dim3 grid(nblocks, 1, 1);
    hipLaunchKernelGGL(diamond_kernel, grid, block, 0, stream, in, out, nblocks);
}

// Round 11
// 96.563 us; speedup vs baseline: 1.2265x; 1.2265x over previous
//
#include <hip/hip_runtime.h>

#define HH 1024
#define WW 1024
#define BM 32            // output rows per block
#define BN 256           // output cols per block
#define RPT 8            // output rows per thread (BM / WAVES)
#define WAVES 4
#define TROWS (BM + 10)  // 42 staged input rows
#define TCOLS 272        // staged floats per row (8 + 256 + 8)
#define TFLOATS (TROWS * TCOLS)        // 11424
#define NSTG ((TFLOATS + 255) / 256)   // 45 staging instructions (1 KB each)
#define LDSF (NSTG * 256)              // 11520 floats of LDS (padded)
#define NXCD 8
#define GX (WW / BN)     // 4
#define GY (HH / BM)     // 32

typedef __attribute__((address_space(1))) const float gfloat;
typedef __attribute__((address_space(3))) float sfloat;
typedef float vfloat4 __attribute__((ext_vector_type(4)));   // native vec for nontemporal

__global__ __launch_bounds__(256) void diamond_kernel(const float* __restrict__ in,
                                                      float* __restrict__ out,
                                                      int nblocks) {
    __shared__ __attribute__((aligned(16))) float tile[LDSF];

    // XCD-aware swizzle, R8 ordering (gx innermost) — proven best.
    const int wgid = blockIdx.x;
    const int k0   = (wgid % NXCD) * (nblocks / NXCD) + wgid / NXCD;
    const int b    = k0 / (GX * GY);
    const int rem  = k0 % (GX * GY);
    const int gy   = rem / GX;
    const int gx   = rem % GX;

    const int tj  = threadIdx.x;                 // lane 0..63
    const int ty  = threadIdx.y;                 // wave 0..3
    const int J0  = gx * BN;
    const int i0b = gy * BM;
    const float* __restrict__ src = in  + (size_t)b * HH * WW;
    float*       __restrict__ dst = out + (size_t)b * HH * WW;

    // ---- stage (i0b-5 .. i0b+BM+4) x (J0-8 .. J0+263) into LDS (DMA, no VGPRs)
#pragma unroll
    for (int n = 0; n < 12; ++n) {
        const int I = ty + 4 * n;                // wave-uniform predicate
        if (I < NSTG) {
            const int f = I * 256 + 4 * tj;      // flat float index in tile
            const int r = f / TCOLS;
            const int c = f - r * TCOLS;
            const int gr = (i0b + r - 5) & (HH - 1);
            const int gc = (J0 - 8 + c) & (WW - 1);   // c%4==0 -> 16B aligned
            __builtin_amdgcn_global_load_lds((gfloat*)(src + (size_t)gr * WW + gc),
                                             (sfloat*)&tile[I * 256], 16, 0, 0);
        }
    }
    __syncthreads();   // drains vmcnt(0): all DMAs landed, visible to all waves

    const float EV[6] = {1.0f,
                         0.36787944117144233f,   // e^-1
                         0.1353352832366127f,    // e^-2
                         0.049787068367863944f,  // e^-3
                         0.018315638888734179f,  // e^-4
                         0.006737946999085467f}; // e^-5

    float acc[RPT][4];
#pragma unroll
    for (int m = 0; m < RPT; ++m)
#pragma unroll
        for (int p = 0; p < 4; ++p) acc[m][p] = 0.0f;

    const int base_r = ty * RPT;   // wave's first tile row (= its first out row)

#pragma unroll
    for (int rr = 0; rr < RPT + 10; ++rr) {
        const float* trow = &tile[(base_r + rr) * TCOLS + 4 * tj];

        // own (center) chunk straight from global: same lines were just DMA'd,
        // so this hits L1/L2/L3 — moves 20% of window traffic off the DS pipe.
        const int gr = (i0b + base_r + rr - 5) & (HH - 1);
        const float4 own =
            *reinterpret_cast<const float4*>(src + (size_t)gr * WW + J0 + 4 * tj);

        // 20-float window: halo from LDS (t = 0,1,3,4), center from global
        float s[20];
        {
            float4 v0 = *reinterpret_cast<const float4*>(trow + 0);
            float4 v1 = *reinterpret_cast<const float4*>(trow + 4);
            float4 v3 = *reinterpret_cast<const float4*>(trow + 12);
            float4 v4 = *reinterpret_cast<const float4*>(trow + 16);
            s[0]  = v0.x; s[1]  = v0.y; s[2]  = v0.z; s[3]  = v0.w;
            s[4]  = v1.x; s[5]  = v1.y; s[6]  = v1.z; s[7]  = v1.w;
            s[8]  = own.x; s[9] = own.y; s[10] = own.z; s[11] = own.w;
            s[12] = v3.x; s[13] = v3.y; s[14] = v3.z; s[15] = v3.w;
            s[16] = v4.x; s[17] = v4.y; s[18] = v4.z; s[19] = v4.w;
        }

        // level-k horizontal sums consumed on the fly:
        // level k feeds output rows m = rr-k and m = rr-10+k with weight EV[5-k]
        float Hc[4];
#pragma unroll
        for (int p = 0; p < 4; ++p) Hc[p] = s[8 + p];
        {   // k = 0, a = 5
            const int m1 = rr - 10, m2 = rr;
            if (m1 >= 0 && m1 < RPT)
#pragma unroll
                for (int p = 0; p < 4; ++p) acc[m1][p] = fmaf(EV[5], Hc[p], acc[m1][p]);
            if (m2 >= 0 && m2 < RPT)
#pragma unroll
                for (int p = 0; p < 4; ++p) acc[m2][p] = fmaf(EV[5], Hc[p], acc[m2][p]);
        }
#pragma unroll
        for (int k = 1; k <= 4; ++k) {
#pragma unroll
            for (int p = 0; p < 4; ++p)
                Hc[p] = fmaf(EV[k], s[8 + p - k] + s[8 + p + k], Hc[p]);
            const int a = 5 - k;
            const int m1 = rr - 10 + k, m2 = rr - k;
            if (m1 >= 0 && m1 < RPT)
#pragma unroll
                for (int p = 0; p < 4; ++p) acc[m1][p] = fmaf(EV[a], Hc[p], acc[m1][p]);
            if (m2 >= 0 && m2 < RPT && m2 != m1)
#pragma unroll
                for (int p = 0; p < 4; ++p) acc[m2][p] = fmaf(EV[a], Hc[p], acc[m2][p]);
        }
        {   // k = 5 -> center row (a = 0): weight 1, subtract the self term
#pragma unroll
            for (int p = 0; p < 4; ++p)
                Hc[p] = fmaf(EV[5], s[8 + p - 5] + s[8 + p + 5], Hc[p]);
            const int m = rr - 5;
            if (m >= 0 && m < RPT)
#pragma unroll
                for (int p = 0; p < 4; ++p) acc[m][p] += Hc[p] - s[8 + p];
        }
    }

    // non-temporal stores: output is never re-read
#pragma unroll
    for (int m = 0; m < RPT; ++m) {
        vfloat4 v = {acc[m][0], acc[m][1], acc[m][2], acc[m][3]};
        __builtin_nontemporal_store(
            v, reinterpret_cast<vfloat4*>(dst + (size_t)(i0b + base_r + m) * WW + J0 + 4 * tj));
    }
}

extern "C" void kernel_launch(void* const* d_in, const int* in_sizes, int n_in,
                              void* d_out, int out_size, void* d_ws, size_t ws_size,
                              hipStream_t stream) {
    const float* in  = (const float*)d_in[0];
    float*       out = (float*)d_out;
    const int B = in_sizes[0] / (HH * WW);   // 64
    const int nblocks = GX * GY * B;         // 8192, divisible by 8
    dim3 block(64, WAVES, 1);
    dim3 grid(nblocks, 1, 1);
    hipLaunchKernelGGL(diamond_kernel, grid, block, 0, stream, in, out, nblocks);
}